// Round 3
// baseline (519.787 us; speedup 1.0000x reference)
//
#include <hip/hip_runtime.h>
#include <math.h>

typedef unsigned int u32;
typedef unsigned long long u64;

// Problem constants
#define N_13 16224
#define N_26 64896
#define N_52 259584
#define N_TOT 340704
#define KSEL 1024

// Workspace layout (bytes). Total ~3.97 MB.
#define WS_KEYS 0UL                 // u64[N_TOT] = 2,725,632
#define WS_HIST 2725632UL           // u32[4][65536] = 1,048,576 (memset-zeroed w/ STP+STK)
#define WS_STP  3774208UL           // u64 selected-key prefix
#define WS_STK  3774216UL           // u32 krem, u32 gather counter
#define WS_GATH 3774224UL           // u64[1024]
#define WS_BOX7 3782416UL           // float[1024*7]
#define WS_X1   3811088UL           // float[1024] each
#define WS_Y1   3815184UL
#define WS_X2   3819280UL
#define WS_Y2   3823376UL
#define WS_AR   3827472UL
#define WS_SUP  3831568UL           // u32[1024]
#define WS_MASK 3835664UL           // u64[1024*16] = 128 KB

// XLA logistic_expander form: 1/(1+exp(-x)), exp -> __ocml_exp_f32 (same as expf).
__device__ __forceinline__ float sigmoid_(float x) {
  return 1.0f / (1.0f + expf(-x));
}

__device__ __forceinline__ u32 fkey_(float f) {
  u32 u = __float_as_uint(f);
  return (u & 0x80000000u) ? ~u : (u | 0x80000000u);
}

// ---------------- score: key = (mkey(score)<<32) | ~idx ; fused pass-0 hist ----
__global__ void score_kernel(const float* __restrict__ f13,
                             const float* __restrict__ f26,
                             const float* __restrict__ f52,
                             const float* __restrict__ thr_p,
                             u64* __restrict__ keys, u32* __restrict__ hist0) {
  int t = blockIdx.x * blockDim.x + threadIdx.x;
  if (t >= N_TOT) return;
  float thr = *thr_p;
  const float* fp; int G2, off, tl;
  if (t < N_13)            { fp = f13; G2 = 169;  off = 0;          tl = t; }
  else if (t < N_13+N_26)  { fp = f26; G2 = 676;  off = N_13;       tl = t - N_13; }
  else                     { fp = f52; G2 = 2704; off = N_13+N_26;  tl = t - (N_13+N_26); }
  int p = tl % G2; int c = tl / G2; int a = c % 3; int b = c / 3;
  float l0 = fp[(size_t)(b*255 + a*85) * G2 + p];
  float conf = sigmoid_(l0);
  float score = (conf > thr) ? conf : -1.0f;
  u32 iref = (u32)(off + (b*G2 + p)*3 + a);   // reference flatten order
  u64 key = ((u64)fkey_(score) << 32) | (u32)(~iref);
  keys[t] = key;
  atomicAdd(&hist0[(u32)(key >> 48)], 1u);
}

// ---------------- radix-select: histogram 16-bit digit (passes 1..3) ----------
__global__ void hist_kernel(const u64* __restrict__ keys, u32* __restrict__ hist,
                            const u64* __restrict__ stp, int pass) {
  int t = blockIdx.x * blockDim.x + threadIdx.x;
  if (t >= N_TOT) return;
  u64 key = keys[t];
  u64 pfx = stp[0];
  if (((key ^ pfx) >> (64 - 16*pass)) != 0ull) return;
  u32 d = (u32)(key >> (48 - 16*pass)) & 0xFFFFu;
  atomicAdd(&hist[d], 1u);
}

// ---------------- radix-select: pick digit at this pass, update state ---------
__global__ __launch_bounds__(1024) void pick_kernel(const u32* __restrict__ hist,
                                                    u64* __restrict__ stp,
                                                    u32* __restrict__ stk,
                                                    int pass) {
  __shared__ u32 suf[1024];
  __shared__ u32 hb[64];
  __shared__ int c_sh;
  int t = threadIdx.x;
  u32 s = 0;
  #pragma unroll 8
  for (int d = 0; d < 64; ++d) s += hist[t*64 + d];   // consecutive -> b128 loads
  suf[t] = s;
  __syncthreads();
  for (int off = 1; off < 1024; off <<= 1) {   // inclusive suffix scan
    u32 v = (t + off < 1024) ? suf[t + off] : 0u;
    __syncthreads();
    suf[t] += v;
    __syncthreads();
  }
  u32 krem = (pass == 0) ? (u32)KSEL : stk[0];
  if (suf[t] >= krem && (t == 1023 || suf[t+1] < krem)) c_sh = t;
  __syncthreads();
  int c = c_sh;
  if (t < 64) hb[t] = hist[c*64 + t];
  __syncthreads();
  if (t == 0) {
    u32 cum = (c < 1023) ? suf[c+1] : 0u;
    int d = 63; u32 hbv = 0;
    for (;; --d) { hbv = hb[d]; cum += hbv; if (cum >= krem) break; }
    int bsel = c*64 + d;
    if (pass == 0) stp[0] = ((u64)(u32)bsel) << 48;
    else           stp[0] |= ((u64)(u32)bsel) << (48 - 16*pass);
    stk[0] = krem - (cum - hbv);
  }
}

// ---------------- gather the exactly-1024 keys >= threshold -------------------
__global__ void gather_kernel(const u64* __restrict__ keys,
                              const u64* __restrict__ stp,
                              u32* __restrict__ stk, u64* __restrict__ gath) {
  int t = blockIdx.x * blockDim.x + threadIdx.x;
  if (t >= N_TOT) return;
  u64 key = keys[t];
  if (key >= stp[0]) {
    u32 pos = atomicAdd(&stk[1], 1u);
    if (pos < KSEL) gath[pos] = key;
  }
}

// ---------------- sort 1024 keys descending (bitonic, 1 block) ----------------
__global__ __launch_bounds__(1024) void sort_kernel(u64* __restrict__ gath) {
  __shared__ u64 sk[1024];
  int t = threadIdx.x;
  sk[t] = gath[t];
  __syncthreads();
  for (int kk = 2; kk <= 1024; kk <<= 1) {
    for (int j = kk >> 1; j > 0; j >>= 1) {
      int ixj = t ^ j;
      if (ixj > t) {
        u64 x0 = sk[t], x1 = sk[ixj];
        bool descRegion = (t & kk) == 0;
        bool sw = descRegion ? (x0 < x1) : (x0 > x1);
        if (sw) { sk[t] = x1; sk[ixj] = x0; }
      }
      __syncthreads();
    }
  }
  gath[t] = sk[t];
}

// ---------------- decode 1024 boxes, one wave per box -------------------------
__global__ void decode_kernel(const float* __restrict__ f13,
                              const float* __restrict__ f26,
                              const float* __restrict__ f52,
                              const float* __restrict__ a13,
                              const float* __restrict__ a26,
                              const float* __restrict__ a52,
                              const float* __restrict__ case_p,
                              const u64* __restrict__ gath,
                              float* __restrict__ box7,
                              float* __restrict__ bx1, float* __restrict__ by1,
                              float* __restrict__ bx2, float* __restrict__ by2,
                              float* __restrict__ bar, u32* __restrict__ bsup) {
  int gt = blockIdx.x * blockDim.x + threadIdx.x;
  int r = gt >> 6;
  int lane = gt & 63;
  if (r >= KSEL) return;
  u64 key = gath[r];
  u32 idx = ~(u32)key;
  u32 sb = (u32)(key >> 32);
  sb = (sb & 0x80000000u) ? (sb & 0x7FFFFFFFu) : ~sb;
  float score = __uint_as_float(sb);
  float case_v = *case_p;

  const float* fp; const float* ap; u32 G, G2, off; float tt;
  if (idx < N_13)            { fp=f13; ap=a13; G=13; G2=169;  off=0;          tt=32.0f; }
  else if (idx < N_13+N_26)  { fp=f26; ap=a26; G=26; G2=676;  off=N_13;       tt=16.0f; }
  else                       { fp=f52; ap=a52; G=52; G2=2704; off=N_13+N_26;  tt=8.0f;  }
  u32 L = idx - off;
  u32 a = L % 3u; u32 q = L / 3u;
  u32 x = q % G; u32 rq = q / G; u32 y = rq % G; u32 b = rq / G;

  const float* base = fp + (size_t)(b*255u + a*85u) * G2 + y*G + x;
  float l0 = base[0];
  float conf = sigmoid_(l0);
  float l2 = base[(size_t)2*G2];
  float l3 = base[(size_t)3*G2];
  float l4 = base[(size_t)4*G2];
  float cy = ((float)y + l2) * tt / case_v;
  float cx = ((float)x + l2) * tt / case_v;   // reference quirk: both use ch 2
  float w = ap[2*a]     * expf(l3) / case_v;
  float h = ap[2*a + 1] * expf(l4) / case_v;

  // ---- argmax over softmax(logits[5:85]) exactly like the reference ----
  // lane holds class c1=lane and (lane<16) c2=lane+64
  bool v2ok = (lane < 16);
  float x1 = base[(size_t)(5 + lane) * G2];
  float x2 = v2ok ? base[(size_t)(5 + 64 + lane) * G2] : -INFINITY;
  float mx = fmaxf(x1, x2);
  #pragma unroll
  for (int o = 32; o > 0; o >>= 1) mx = fmaxf(mx, __shfl_xor(mx, o));
  float e1 = expf(x1 - mx);
  float e2 = v2ok ? expf(x2 - mx) : 0.0f;
  float ssum = e1 + e2;
  #pragma unroll
  for (int o = 32; o > 0; o >>= 1) ssum += __shfl_xor(ssum, o);
  float p1 = e1 / ssum;
  float p2 = v2ok ? (e2 / ssum) : -1.0f;
  // within-lane first-max (c1 < c2 always, so strict > for c2 to win)
  float pm = p1; int ci = lane;
  if (p2 > pm) { pm = p2; ci = lane + 64; }
  #pragma unroll
  for (int o = 32; o > 0; o >>= 1) {
    float om = __shfl_xor(pm, o);
    int   oc = __shfl_xor(ci, o);
    if (om > pm || (om == pm && oc < ci)) { pm = om; ci = oc; }
  }

  if (lane == 0) {
    box7[r*7 + 0] = (float)b;
    box7[r*7 + 1] = conf;
    box7[r*7 + 2] = cx;
    box7[r*7 + 3] = cy;
    box7[r*7 + 4] = w;
    box7[r*7 + 5] = h;
    box7[r*7 + 6] = (float)ci;
    float hw = __fmul_rn(w, 0.5f);
    float hh = __fmul_rn(h, 0.5f);
    bx1[r] = __fsub_rn(cx, hw);
    bx2[r] = __fadd_rn(cx, hw);
    by1[r] = __fsub_rn(cy, hh);
    by2[r] = __fadd_rn(cy, hh);
    bar[r] = __fmul_rn(w, h);
    bsup[r] = (score <= 0.0f) ? 1u : 0u;
  }
}

// ---------------- static suppression bit-matrix: iou>0.5 && j>i ---------------
__global__ __launch_bounds__(256) void mask_kernel(const float* __restrict__ bx1,
                                                   const float* __restrict__ by1,
                                                   const float* __restrict__ bx2,
                                                   const float* __restrict__ by2,
                                                   const float* __restrict__ bar,
                                                   u64* __restrict__ mask) {
  __shared__ float sx1[1024], sy1[1024], sx2[1024], sy2[1024], sar[1024];
  int t = threadIdx.x;
  for (int k = t; k < 1024; k += 256) {
    sx1[k] = bx1[k]; sy1[k] = by1[k];
    sx2[k] = bx2[k]; sy2[k] = by2[k]; sar[k] = bar[k];
  }
  __syncthreads();
  int T = blockIdx.x * 256 + t;
  int i = T >> 4, w = T & 15;
  float x1 = sx1[i], y1 = sy1[i], x2 = sx2[i], y2 = sy2[i], ar = sar[i];
  u64 m = 0;
  int j0 = w << 6;
  for (int b = 0; b < 64; ++b) {
    int j = j0 + b;
    float iw = fmaxf(__fsub_rn(fminf(sx2[j], x2), fmaxf(sx1[j], x1)), 0.0f);
    float ih = fmaxf(__fsub_rn(fminf(sy2[j], y2), fmaxf(sy1[j], y1)), 0.0f);
    float inter = __fmul_rn(iw, ih);
    float den = __fadd_rn(__fsub_rn(__fadd_rn(ar, sar[j]), inter), 1e-9f);
    float iou = inter / den;                    // IEEE divide, both sides
    if (iou > 0.5f && j > i) m |= (1ull << b);
  }
  mask[i*16 + w] = m;
}

// ---------------- serial resolve on one wave + masked output ------------------
__global__ __launch_bounds__(1024) void resolve_kernel(const u64* __restrict__ mask,
                                                       const u32* __restrict__ bsup,
                                                       const float* __restrict__ box7,
                                                       float* __restrict__ out) {
  __shared__ u64 sm[16384];     // 128 KB mask copy (gfx950: 160 KB LDS)
  __shared__ u64 ssupw[16];
  int t = threadIdx.x;
  for (int k = t; k < 16384; k += 1024) sm[k] = mask[k];
  __syncthreads();
  if (t < 64) {
    int lane = t;
    u64 supp = 0;
    for (int w = 0; w < 16; ++w) {            // pack supp0 via ballot
      u64 bal = __ballot(bsup[w*64 + lane] != 0u);
      if (w == lane) supp = bal;
    }
    u64 c0, c1, c2, c3, n0, n1, n2, n3;
    c0 = (lane < 16) ? sm[0*16 + lane] : 0ull;
    c1 = (lane < 16) ? sm[1*16 + lane] : 0ull;
    c2 = (lane < 16) ? sm[2*16 + lane] : 0ull;
    c3 = (lane < 16) ? sm[3*16 + lane] : 0ull;
    for (int i = 0; i < 1024; i += 4) {
      if (i + 4 < 1024) {                     // prefetch next 4 rows
        n0 = (lane < 16) ? sm[(i+4)*16 + lane] : 0ull;
        n1 = (lane < 16) ? sm[(i+5)*16 + lane] : 0ull;
        n2 = (lane < 16) ? sm[(i+6)*16 + lane] : 0ull;
        n3 = (lane < 16) ? sm[(i+7)*16 + lane] : 0ull;
      } else { n0 = n1 = n2 = n3 = 0ull; }
      u64 sw;
      sw = __shfl(supp, (i  ) >> 6); if (!((sw >> ((i  ) & 63)) & 1ull)) supp |= c0;
      sw = __shfl(supp, (i+1) >> 6); if (!((sw >> ((i+1) & 63)) & 1ull)) supp |= c1;
      sw = __shfl(supp, (i+2) >> 6); if (!((sw >> ((i+2) & 63)) & 1ull)) supp |= c2;
      sw = __shfl(supp, (i+3) >> 6); if (!((sw >> ((i+3) & 63)) & 1ull)) supp |= c3;
      c0 = n0; c1 = n1; c2 = n2; c3 = n3;
    }
    if (lane < 16) ssupw[lane] = supp;
  }
  __syncthreads();
  u32 keep = !((ssupw[t >> 6] >> (t & 63)) & 1ull);
  #pragma unroll
  for (int c = 0; c < 7; ++c) {
    float v = box7[t*7 + c];
    out[t*7 + c] = keep ? v : 0.0f;
  }
}

extern "C" void kernel_launch(void* const* d_in, const int* in_sizes, int n_in,
                              void* d_out, int out_size, void* d_ws, size_t ws_size,
                              hipStream_t stream) {
  const float* f13 = (const float*)d_in[0];
  const float* f26 = (const float*)d_in[1];
  const float* f52 = (const float*)d_in[2];
  const float* thr = (const float*)d_in[3];
  const float* cas = (const float*)d_in[4];
  const float* a13 = (const float*)d_in[5];
  const float* a26 = (const float*)d_in[6];
  const float* a52 = (const float*)d_in[7];
  float* out = (float*)d_out;
  char* ws = (char*)d_ws;

  u64* keys = (u64*)(ws + WS_KEYS);
  u32* hist = (u32*)(ws + WS_HIST);   // 4 buffers of 65536
  u64* stp  = (u64*)(ws + WS_STP);
  u32* stk  = (u32*)(ws + WS_STK);
  u64* gath = (u64*)(ws + WS_GATH);
  float* box7 = (float*)(ws + WS_BOX7);
  float* bx1 = (float*)(ws + WS_X1);
  float* by1 = (float*)(ws + WS_Y1);
  float* bx2 = (float*)(ws + WS_X2);
  float* by2 = (float*)(ws + WS_Y2);
  float* bar = (float*)(ws + WS_AR);
  u32* bsup = (u32*)(ws + WS_SUP);
  u64* mask = (u64*)(ws + WS_MASK);

  const int nb = (N_TOT + 255) / 256;

  // zero all 4 hist buffers + stp + stk in one async memset (graph-capturable)
  hipMemsetAsync(ws + WS_HIST, 0, 1048576 + 16, stream);
  score_kernel<<<nb, 256, 0, stream>>>(f13, f26, f52, thr, keys, hist);
  pick_kernel<<<1, 1024, 0, stream>>>(hist, stp, stk, 0);
  for (int p = 1; p < 4; ++p) {
    hist_kernel<<<nb, 256, 0, stream>>>(keys, hist + p*65536, stp, p);
    pick_kernel<<<1, 1024, 0, stream>>>(hist + p*65536, stp, stk, p);
  }
  gather_kernel<<<nb, 256, 0, stream>>>(keys, stp, stk, gath);
  sort_kernel<<<1, 1024, 0, stream>>>(gath);
  decode_kernel<<<256, 256, 0, stream>>>(f13, f26, f52, a13, a26, a52, cas, gath,
                                         box7, bx1, by1, bx2, by2, bar, bsup);
  mask_kernel<<<64, 256, 0, stream>>>(bx1, by1, bx2, by2, bar, mask);
  resolve_kernel<<<1, 1024, 0, stream>>>(mask, bsup, box7, out);
}

// Round 6
// 281.428 us; speedup vs baseline: 1.8470x; 1.8470x over previous
//
#include <hip/hip_runtime.h>
#include <math.h>

typedef unsigned int u32;
typedef unsigned long long u64;

// Problem constants
#define N_13 16224
#define N_26 64896
#define N_52 259584
#define N_TOT 340704
#define KSEL 1024
#define NBINS 8192
#define NBH 64            // histogram blocks
#define CAND 2048

// Workspace layout (bytes). Total ~236 KB.
#define WS_HIST 0UL                 // u32[NBINS] = 32768   (memset-zeroed w/ STK)
#define WS_STK  32768UL             // u32[4]: counter, bsel, pad
#define WS_CAND 32784UL             // u64[CAND] = 16384
#define WS_GATH 49168UL             // u64[1024] = 8192
#define WS_BOX7 57360UL             // float[1024*7] = 28672
#define WS_X1   86032UL             // float[1024] each
#define WS_Y1   90128UL
#define WS_X2   94224UL
#define WS_Y2   98320UL
#define WS_AR   102416UL
#define WS_SUP  106512UL            // u32[1024]
#define WS_MASK 110608UL            // u64[1024*16] = 131072 (end 241680)

// XLA logistic_expander form: 1/(1+exp(-x)), exp -> __ocml_exp_f32 (same as expf).
__device__ __forceinline__ float sigmoid_(float x) {
  return 1.0f / (1.0f + expf(-x));
}

__device__ __forceinline__ u32 fkey_(float f) {
  u32 u = __float_as_uint(f);
  return (u & 0x80000000u) ? ~u : (u | 0x80000000u);
}

// monotone coarse bin of the score: linear in logit-space (N(0,1) -> spread).
// Used ONLY as a gather predicate, never in the sort key.
__device__ __forceinline__ int binof_(float l0, float score) {
  if (score == -1.0f) return 0;                 // below every conf>thr key
  int b = (int)floorf((l0 + 8.0f) * 512.0f);    // [-8,8) -> [0,8192)
  return b < 0 ? 0 : (b > NBINS-1 ? NBINS-1 : b);
}

// map flat t -> (level ptr, G2, off, local idx)
__device__ __forceinline__ const float* level_(int t, const float* f13,
                                               const float* f26, const float* f52,
                                               int& G2, int& off, int& tl) {
  if (t < N_13)            { G2 = 169;  off = 0;         tl = t;                return f13; }
  else if (t < N_13+N_26)  { G2 = 676;  off = N_13;      tl = t - N_13;         return f26; }
  else                     { G2 = 2704; off = N_13+N_26; tl = t - (N_13+N_26);  return f52; }
}

// ---------------- pass A: per-block LDS histogram -> global atomic merge ------
__global__ __launch_bounds__(1024) void hist_kernel(const float* __restrict__ f13,
                                                    const float* __restrict__ f26,
                                                    const float* __restrict__ f52,
                                                    const float* __restrict__ thr_p,
                                                    u32* __restrict__ hist) {
  __shared__ u32 lh[NBINS];
  int tid = threadIdx.x;
  for (int i = tid; i < NBINS; i += 1024) lh[i] = 0u;
  __syncthreads();
  float thr = *thr_p;
  for (int t = blockIdx.x * 1024 + tid; t < N_TOT; t += NBH * 1024) {
    int G2, off, tl;
    const float* fp = level_(t, f13, f26, f52, G2, off, tl);
    int p = tl % G2; int c = tl / G2; int a = c % 3; int b = c / 3;
    float l0 = fp[(size_t)(b*255 + a*85) * G2 + p];
    float conf = sigmoid_(l0);
    float score = (conf > thr) ? conf : -1.0f;
    atomicAdd(&lh[binof_(l0, score)], 1u);
  }
  __syncthreads();
  for (int i = tid; i < NBINS; i += 1024) {
    u32 v = lh[i];
    if (v) atomicAdd(&hist[i], v);   // <=64-way contention per bin
  }
}

// ---------------- pick threshold bin; zero candidate buffer -------------------
__global__ __launch_bounds__(1024) void pick_kernel(const u32* __restrict__ hist,
                                                    u32* __restrict__ stk,
                                                    u64* __restrict__ cand) {
  __shared__ u32 lh[NBINS];
  __shared__ u32 suf[1024];
  int t = threadIdx.x;
  u32 s = 0;
  #pragma unroll 8
  for (int d = 0; d < 8; ++d) { u32 v = hist[t*8 + d]; lh[t*8 + d] = v; s += v; }
  suf[t] = s;
  __syncthreads();
  for (int off = 1; off < 1024; off <<= 1) {   // inclusive suffix scan of chunks
    u32 v = (t + off < 1024) ? suf[t + off] : 0u;
    __syncthreads();
    suf[t] += v;
    __syncthreads();
  }
  if (suf[t] >= (u32)KSEL && (t == 1023 || suf[t+1] < (u32)KSEL)) {
    u32 cum = (t < 1023) ? suf[t+1] : 0u;
    int bsel = t*8;
    for (int d = 7; d >= 0; --d) {
      cum += lh[t*8 + d];
      if (cum >= (u32)KSEL) { bsel = t*8 + d; break; }
    }
    stk[1] = (u32)bsel;
  }
  // zero candidate buffer (padding keys sort below all real keys)
  cand[t] = 0ull; cand[t + 1024] = 0ull;
}

// ---------------- gather all keys with bin >= bsel ----------------------------
__global__ void gather_kernel(const float* __restrict__ f13,
                              const float* __restrict__ f26,
                              const float* __restrict__ f52,
                              const float* __restrict__ thr_p,
                              u32* __restrict__ stk, u64* __restrict__ cand) {
  int t = blockIdx.x * blockDim.x + threadIdx.x;
  if (t >= N_TOT) return;
  float thr = *thr_p;
  int G2, off, tl;
  const float* fp = level_(t, f13, f26, f52, G2, off, tl);
  int p = tl % G2; int c = tl / G2; int a = c % 3; int b = c / 3;
  float l0 = fp[(size_t)(b*255 + a*85) * G2 + p];
  float conf = sigmoid_(l0);
  float score = (conf > thr) ? conf : -1.0f;
  int bin = binof_(l0, score);
  if ((u32)bin >= stk[1]) {
    u32 iref = (u32)(off + (b*G2 + p)*3 + a);   // reference flatten order
    // pure (score desc, idx asc) key — bin is NOT part of the ordering
    u64 key = ((u64)fkey_(score) << 19) | (u64)(524287u - iref);
    u32 pos = atomicAdd(&stk[0], 1u);
    if (pos < (u32)CAND) cand[pos] = key;
  }
}

// ---------------- sort CAND keys descending (bitonic, 1 block); top 1024 ------
__global__ __launch_bounds__(1024) void sort_kernel(const u64* __restrict__ cand,
                                                    u64* __restrict__ gath) {
  __shared__ u64 sk[CAND];
  int t = threadIdx.x;
  sk[t] = cand[t]; sk[t + 1024] = cand[t + 1024];
  __syncthreads();
  for (int kk = 2; kk <= CAND; kk <<= 1) {
    for (int j = kk >> 1; j > 0; j >>= 1) {
      #pragma unroll
      for (int h = 0; h < 2; ++h) {
        int e = t + h*1024;
        int ixj = e ^ j;
        if (ixj > e) {
          u64 x0 = sk[e], x1 = sk[ixj];
          bool descRegion = (e & kk) == 0;
          bool sw = descRegion ? (x0 < x1) : (x0 > x1);
          if (sw) { sk[e] = x1; sk[ixj] = x0; }
        }
      }
      __syncthreads();
    }
  }
  gath[t] = sk[t];
}

// ---------------- decode 1024 boxes, one wave per box -------------------------
__global__ void decode_kernel(const float* __restrict__ f13,
                              const float* __restrict__ f26,
                              const float* __restrict__ f52,
                              const float* __restrict__ a13,
                              const float* __restrict__ a26,
                              const float* __restrict__ a52,
                              const float* __restrict__ case_p,
                              const u64* __restrict__ gath,
                              float* __restrict__ box7,
                              float* __restrict__ bx1, float* __restrict__ by1,
                              float* __restrict__ bx2, float* __restrict__ by2,
                              float* __restrict__ bar, u32* __restrict__ bsup) {
  int gt = blockIdx.x * blockDim.x + threadIdx.x;
  int r = gt >> 6;
  int lane = gt & 63;
  if (r >= KSEL) return;
  u64 key = gath[r];
  u32 idx = 524287u - ((u32)key & 0x7FFFFu);
  u32 sb = (u32)(key >> 19);
  sb = (sb & 0x80000000u) ? (sb & 0x7FFFFFFFu) : ~sb;
  float score = __uint_as_float(sb);
  float case_v = *case_p;

  const float* fp; const float* ap; u32 G, G2, off; float tt;
  if (idx < N_13)            { fp=f13; ap=a13; G=13; G2=169;  off=0;          tt=32.0f; }
  else if (idx < N_13+N_26)  { fp=f26; ap=a26; G=26; G2=676;  off=N_13;       tt=16.0f; }
  else                       { fp=f52; ap=a52; G=52; G2=2704; off=N_13+N_26;  tt=8.0f;  }
  u32 L = idx - off;
  u32 a = L % 3u; u32 q = L / 3u;
  u32 x = q % G; u32 rq = q / G; u32 y = rq % G; u32 b = rq / G;

  const float* base = fp + (size_t)(b*255u + a*85u) * G2 + y*G + x;
  float l0 = base[0];
  float conf = sigmoid_(l0);
  float l2 = base[(size_t)2*G2];
  float l3 = base[(size_t)3*G2];
  float l4 = base[(size_t)4*G2];
  float cy = ((float)y + l2) * tt / case_v;
  float cx = ((float)x + l2) * tt / case_v;   // reference quirk: both use ch 2
  float w = ap[2*a]     * expf(l3) / case_v;
  float h = ap[2*a + 1] * expf(l4) / case_v;

  // argmax over softmax(logits[5:85]) exactly like the reference
  bool v2ok = (lane < 16);
  float x1 = base[(size_t)(5 + lane) * G2];
  float x2 = v2ok ? base[(size_t)(5 + 64 + lane) * G2] : -INFINITY;
  float mx = fmaxf(x1, x2);
  #pragma unroll
  for (int o = 32; o > 0; o >>= 1) mx = fmaxf(mx, __shfl_xor(mx, o));
  float e1 = expf(x1 - mx);
  float e2 = v2ok ? expf(x2 - mx) : 0.0f;
  float ssum = e1 + e2;
  #pragma unroll
  for (int o = 32; o > 0; o >>= 1) ssum += __shfl_xor(ssum, o);
  float p1 = e1 / ssum;
  float p2 = v2ok ? (e2 / ssum) : -1.0f;
  float pm = p1; int ci = lane;
  if (p2 > pm) { pm = p2; ci = lane + 64; }
  #pragma unroll
  for (int o = 32; o > 0; o >>= 1) {
    float om = __shfl_xor(pm, o);
    int   oc = __shfl_xor(ci, o);
    if (om > pm || (om == pm && oc < ci)) { pm = om; ci = oc; }
  }

  if (lane == 0) {
    box7[r*7 + 0] = (float)b;
    box7[r*7 + 1] = conf;
    box7[r*7 + 2] = cx;
    box7[r*7 + 3] = cy;
    box7[r*7 + 4] = w;
    box7[r*7 + 5] = h;
    box7[r*7 + 6] = (float)ci;
    float hw = __fmul_rn(w, 0.5f);
    float hh = __fmul_rn(h, 0.5f);
    bx1[r] = __fsub_rn(cx, hw);
    bx2[r] = __fadd_rn(cx, hw);
    by1[r] = __fsub_rn(cy, hh);
    by2[r] = __fadd_rn(cy, hh);
    bar[r] = __fmul_rn(w, h);
    bsup[r] = (score <= 0.0f) ? 1u : 0u;
  }
}

// ---------------- static suppression bit-matrix: iou>0.5 && j>i ---------------
__global__ __launch_bounds__(256) void mask_kernel(const float* __restrict__ bx1,
                                                   const float* __restrict__ by1,
                                                   const float* __restrict__ bx2,
                                                   const float* __restrict__ by2,
                                                   const float* __restrict__ bar,
                                                   u64* __restrict__ mask) {
  __shared__ float sx1[1024], sy1[1024], sx2[1024], sy2[1024], sar[1024];
  int t = threadIdx.x;
  for (int k = t; k < 1024; k += 256) {
    sx1[k] = bx1[k]; sy1[k] = by1[k];
    sx2[k] = bx2[k]; sy2[k] = by2[k]; sar[k] = bar[k];
  }
  __syncthreads();
  int T = blockIdx.x * 256 + t;
  int i = T >> 4, w = T & 15;
  float x1 = sx1[i], y1 = sy1[i], x2 = sx2[i], y2 = sy2[i], ar = sar[i];
  u64 m = 0;
  int j0 = w << 6;
  for (int b = 0; b < 64; ++b) {
    int j = j0 + b;
    float iw = fmaxf(__fsub_rn(fminf(sx2[j], x2), fmaxf(sx1[j], x1)), 0.0f);
    float ih = fmaxf(__fsub_rn(fminf(sy2[j], y2), fmaxf(sy1[j], y1)), 0.0f);
    float inter = __fmul_rn(iw, ih);
    float den = __fadd_rn(__fsub_rn(__fadd_rn(ar, sar[j]), inter), 1e-9f);
    float iou = inter / den;                    // IEEE divide, both sides
    if (iou > 0.5f && j > i) m |= (1ull << b);
  }
  mask[i*16 + w] = m;
}

// ---------------- serial resolve on one wave + masked output ------------------
__global__ __launch_bounds__(1024) void resolve_kernel(const u64* __restrict__ mask,
                                                       const u32* __restrict__ bsup,
                                                       const float* __restrict__ box7,
                                                       float* __restrict__ out) {
  __shared__ u64 sm[16384];     // 128 KB mask copy (gfx950: 160 KB LDS)
  __shared__ u64 ssupw[16];
  int t = threadIdx.x;
  for (int k = t; k < 16384; k += 1024) sm[k] = mask[k];
  __syncthreads();
  if (t < 64) {
    int lane = t;
    u64 supp = 0;
    for (int w = 0; w < 16; ++w) {            // pack supp0 via ballot
      u64 bal = __ballot(bsup[w*64 + lane] != 0u);
      if (w == lane) supp = bal;
    }
    u64 c0, c1, c2, c3, n0, n1, n2, n3;
    c0 = (lane < 16) ? sm[0*16 + lane] : 0ull;
    c1 = (lane < 16) ? sm[1*16 + lane] : 0ull;
    c2 = (lane < 16) ? sm[2*16 + lane] : 0ull;
    c3 = (lane < 16) ? sm[3*16 + lane] : 0ull;
    for (int i = 0; i < 1024; i += 4) {
      if (i + 4 < 1024) {                     // prefetch next 4 rows
        n0 = (lane < 16) ? sm[(i+4)*16 + lane] : 0ull;
        n1 = (lane < 16) ? sm[(i+5)*16 + lane] : 0ull;
        n2 = (lane < 16) ? sm[(i+6)*16 + lane] : 0ull;
        n3 = (lane < 16) ? sm[(i+7)*16 + lane] : 0ull;
      } else { n0 = n1 = n2 = n3 = 0ull; }
      u64 sw;
      sw = __shfl(supp, (i  ) >> 6); if (!((sw >> ((i  ) & 63)) & 1ull)) supp |= c0;
      sw = __shfl(supp, (i+1) >> 6); if (!((sw >> ((i+1) & 63)) & 1ull)) supp |= c1;
      sw = __shfl(supp, (i+2) >> 6); if (!((sw >> ((i+2) & 63)) & 1ull)) supp |= c2;
      sw = __shfl(supp, (i+3) >> 6); if (!((sw >> ((i+3) & 63)) & 1ull)) supp |= c3;
      c0 = n0; c1 = n1; c2 = n2; c3 = n3;
    }
    if (lane < 16) ssupw[lane] = supp;
  }
  __syncthreads();
  u32 keep = !((ssupw[t >> 6] >> (t & 63)) & 1ull);
  #pragma unroll
  for (int c = 0; c < 7; ++c) {
    float v = box7[t*7 + c];
    out[t*7 + c] = keep ? v : 0.0f;
  }
}

extern "C" void kernel_launch(void* const* d_in, const int* in_sizes, int n_in,
                              void* d_out, int out_size, void* d_ws, size_t ws_size,
                              hipStream_t stream) {
  const float* f13 = (const float*)d_in[0];
  const float* f26 = (const float*)d_in[1];
  const float* f52 = (const float*)d_in[2];
  const float* thr = (const float*)d_in[3];
  const float* cas = (const float*)d_in[4];
  const float* a13 = (const float*)d_in[5];
  const float* a26 = (const float*)d_in[6];
  const float* a52 = (const float*)d_in[7];
  float* out = (float*)d_out;
  char* ws = (char*)d_ws;

  u32* hist = (u32*)(ws + WS_HIST);
  u32* stk  = (u32*)(ws + WS_STK);
  u64* cand = (u64*)(ws + WS_CAND);
  u64* gath = (u64*)(ws + WS_GATH);
  float* box7 = (float*)(ws + WS_BOX7);
  float* bx1 = (float*)(ws + WS_X1);
  float* by1 = (float*)(ws + WS_Y1);
  float* bx2 = (float*)(ws + WS_X2);
  float* by2 = (float*)(ws + WS_Y2);
  float* bar = (float*)(ws + WS_AR);
  u32* bsup = (u32*)(ws + WS_SUP);
  u64* mask = (u64*)(ws + WS_MASK);

  const int nb = (N_TOT + 255) / 256;

  hipMemsetAsync(ws + WS_HIST, 0, 32768 + 16, stream);   // hist + stk
  hist_kernel<<<NBH, 1024, 0, stream>>>(f13, f26, f52, thr, hist);
  pick_kernel<<<1, 1024, 0, stream>>>(hist, stk, cand);
  gather_kernel<<<nb, 256, 0, stream>>>(f13, f26, f52, thr, stk, cand);
  sort_kernel<<<1, 1024, 0, stream>>>(cand, gath);
  decode_kernel<<<256, 256, 0, stream>>>(f13, f26, f52, a13, a26, a52, cas, gath,
                                         box7, bx1, by1, bx2, by2, bar, bsup);
  mask_kernel<<<64, 256, 0, stream>>>(bx1, by1, bx2, by2, bar, mask);
  resolve_kernel<<<1, 1024, 0, stream>>>(mask, bsup, box7, out);
}